// Round 15
// baseline (1370.987 us; speedup 1.0000x reference)
//
#include <hip/hip_runtime.h>
#include <math.h>

typedef short bf16x8 __attribute__((ext_vector_type(8)));
typedef float f32x4 __attribute__((ext_vector_type(4)));
typedef float f32x2 __attribute__((ext_vector_type(2)));
typedef unsigned short u16;
typedef unsigned int u32;
typedef unsigned short u16x4 __attribute__((ext_vector_type(4)));

#define B_    32
#define D_    384
#define DEPTH 12
#define NST   16
#define DI_   768
#define R_    24
#define L_    196
#define NC_   1000
#define M_    (B_*L_)   // 6272
#define SEG   28
#define NSEG  7

__device__ __forceinline__ u16 f2bf(float f) {
  union { float f; unsigned u; } v; v.f = f;
  unsigned r = v.u + 0x7fffu + ((v.u >> 16) & 1u);
  return (u16)(r >> 16);
}
__device__ __forceinline__ float bf2f(u16 x) {
  union { unsigned u; float f; } v; v.u = ((unsigned)x) << 16;
  return v.f;
}
__device__ __forceinline__ float quad_sum(float y) {
  y += __int_as_float(__builtin_amdgcn_update_dpp(0, __float_as_int(y), 0xB1, 0xf, 0xf, true));
  y += __int_as_float(__builtin_amdgcn_update_dpp(0, __float_as_int(y), 0x4E, 0xf, 0xf, true));
  return y;
}
__device__ __forceinline__ float exp2fast(float x) {
  return __builtin_amdgcn_exp2f(x);
}

// ---------------- weight prep ----------------
__global__ void k_transpose_bf16(const float* __restrict__ in, u16* __restrict__ out,
                                 int R, int C) {
  __shared__ float tile[32][33];
  const size_t zoff = (size_t)blockIdx.z * R * C;
  in  += zoff; out += zoff;
  int c0 = blockIdx.x * 32, r0 = blockIdx.y * 32;
  int tx = threadIdx.x, ty = threadIdx.y;
  for (int i = ty; i < 32; i += 8) {
    int r = r0 + i, c = c0 + tx;
    tile[i][tx] = (r < R && c < C) ? in[(size_t)r * C + c] : 0.f;
  }
  __syncthreads();
  for (int i = ty; i < 32; i += 8) {
    int c = c0 + i, r = r0 + tx;
    if (c < C && r < R) out[(size_t)c * R + r] = f2bf(tile[tx][i]);
  }
}

__global__ void k_convert_bf16(const float* __restrict__ in, u16* __restrict__ out, int n) {
  int i = blockIdx.x * 256 + threadIdx.x;
  if (i < n) out[i] = f2bf(in[i]);
}

// A2 = -exp(A_log) * log2(e)
__global__ void k_prepA(const float* __restrict__ alog, float* __restrict__ A, int n) {
  int i = blockIdx.x * 256 + threadIdx.x;
  if (i < n) A[i] = -__expf(alog[i]) * 1.44269504088896340736f;
}

// ---------------- im2col ----------------
__global__ void k_im2col(const float* __restrict__ x, u16* __restrict__ xcol) {
  int idx = blockIdx.x * 256 + threadIdx.x;
  if (idx >= M_ * 768) return;
  int k = idx % 768, m = idx / 768;
  int b = m / L_, l = m % L_;
  int li = l / 14, lj = l % 14;
  int c = k / 256, r = k % 256;
  int i = r / 16, j = r % 16;
  int hh = li * 16 + i, ww = lj * 16 + j;
  xcol[idx] = f2bf(x[(((size_t)b * 3 + c) * 224 + hh) * 224 + ww]);
}

// ---------------- GEMM (software-pipelined) ----------------
template<int BM, int BN, int EPI, int OB>
__global__ __launch_bounds__(256)
void k_gemm(const u16* __restrict__ A, const u16* __restrict__ BT,
            float* __restrict__ Cout, int Nn, int Kk,
            const float* __restrict__ bias, const float* __restrict__ pos) {
  const int m0 = blockIdx.x * BM;
  const int n0 = blockIdx.y * BN;
  __shared__ u16 lA[BM * 72];
  __shared__ u16 lB[BN * 72];
  const int tid  = threadIdx.x;
  const int wave = tid >> 6, lane = tid & 63;
  const int wm = (wave >> 1) * (BM / 2), wn = (wave & 1) * (BN / 2);
  constexpr int MI = BM / 32, NJ = BN / 32;
  constexpr int NV = (BM + BN) / 32;
  f32x4 acc[MI][NJ] = {};
  const int fr = lane & 15, kg = (lane >> 4) * 8;

  bf16x8 v[NV];
  auto load = [&](int k0) {
    #pragma unroll
    for (int q = 0; q < NV; ++q) {
      int id = tid + q * 256;
      int row = id >> 3, vv = id & 7;
      bf16x8 t = {};
      if (row < BM) {
        t = *(const bf16x8*)(A + (size_t)(m0 + row) * Kk + k0 + vv * 8);
      } else {
        int br = n0 + row - BM;
        if (br < Nn) t = *(const bf16x8*)(BT + (size_t)br * Kk + k0 + vv * 8);
      }
      v[q] = t;
    }
  };
  load(0);
  for (int k0 = 0; k0 < Kk; k0 += 64) {
    __syncthreads();
    #pragma unroll
    for (int q = 0; q < NV; ++q) {
      int id = tid + q * 256;
      int row = id >> 3, vv = id & 7;
      u16* dst = (row < BM) ? (lA + row * 72 + vv * 8) : (lB + (size_t)(row - BM) * 72 + vv * 8);
      *(bf16x8*)dst = v[q];
    }
    __syncthreads();
    if (k0 + 64 < Kk) load(k0 + 64);
    #pragma unroll
    for (int kk = 0; kk < 64; kk += 32) {
      bf16x8 af[MI], bfr[NJ];
      #pragma unroll
      for (int i = 0; i < MI; ++i)
        af[i] = *(const bf16x8*)(lA + (wm + i * 16 + fr) * 72 + kk + kg);
      #pragma unroll
      for (int j = 0; j < NJ; ++j)
        bfr[j] = *(const bf16x8*)(lB + (wn + j * 16 + fr) * 72 + kk + kg);
      #pragma unroll
      for (int i = 0; i < MI; ++i)
        #pragma unroll
        for (int j = 0; j < NJ; ++j)
          acc[i][j] = __builtin_amdgcn_mfma_f32_16x16x32_bf16(af[i], bfr[j], acc[i][j], 0, 0, 0);
    }
  }

  const int rg = (lane >> 4) * 4;
  #pragma unroll
  for (int i = 0; i < MI; ++i) {
    int row = m0 + wm + i * 16 + rg;
    #pragma unroll
    for (int j = 0; j < NJ; ++j) {
      int col = n0 + wn + j * 16 + fr;
      if (col >= Nn) continue;
      #pragma unroll
      for (int r = 0; r < 4; ++r) {
        float vv = acc[i][j][r];
        size_t idx = (size_t)(row + r) * Nn + col;
        if (EPI == 0) {
          if (OB) ((u16*)Cout)[idx] = f2bf(vv);
          else    Cout[idx] = vv;
        }
        else if (EPI == 1) Cout[idx] += vv;
        else               Cout[idx] = vv + bias[col] + pos[(size_t)((row + r) % L_) * Nn + col];
      }
    }
  }
}

// ---------------- fused conv+SiLU + xp skinny GEMM (K-split x4) ----------------
__global__ __launch_bounds__(256)
void k_xp_conv(const u16* __restrict__ xzb, const float* __restrict__ cw,
               const float* __restrict__ cb, const u16* __restrict__ BT,
               u16* __restrict__ xcb, float* __restrict__ pbuf) {
  const int m0  = blockIdx.x * 32;
  const int ks  = blockIdx.y;
  const int ch0 = ks * 192;
  __shared__ u16 sXZ[35][64];
  __shared__ u16 lA[32 * 72];
  __shared__ u16 lB[64 * 72];
  const int tid  = threadIdx.x;
  const int wave = tid >> 6, lane = tid & 63;
  const int wm = (wave >> 1) * 16, wn = (wave & 1) * 32;
  const int fr = lane & 15, kg = (lane >> 4) * 8;
  f32x4 acc[2] = {};

  for (int kc = 0; kc < 3; ++kc) {
    const int c0 = ch0 + kc * 64;
    __syncthreads();
    #pragma unroll
    for (int j = 0; j < 2; ++j) {
      int u = tid + j * 256;
      if (u < 448) {
        int row = u >> 3, vv = u & 7;
        *(bf16x8*)(lB + row * 72 + vv * 8) =
            *(const bf16x8*)(BT + (size_t)row * DI_ + c0 + vv * 8);
      }
    }
    #pragma unroll
    for (int j = 0; j < 3; ++j) {
      int u = tid + j * 256;
      if (u < 560) {
        int row = u >> 4, c4 = (u & 15) * 4;
        int gm = m0 - 3 + row; if (gm < 0) gm = 0;
        *(u16x4*)&sXZ[row][c4] = *(const u16x4*)(xzb + (size_t)gm * 1536 + c0 + c4);
      }
    }
    __syncthreads();
    #pragma unroll
    for (int j = 0; j < 2; ++j) {
      int g = tid + j * 256;
      int r = g >> 4, c4 = (g & 15) * 4;
      int l = (m0 + r) % L_;
      u16x4 t0 = *(const u16x4*)&sXZ[r + 3][c4];
      u16x4 t1 = (l >= 1) ? *(const u16x4*)&sXZ[r + 2][c4] : u16x4{};
      u16x4 t2 = (l >= 2) ? *(const u16x4*)&sXZ[r + 1][c4] : u16x4{};
      u16x4 t3 = (l >= 3) ? *(const u16x4*)&sXZ[r    ][c4] : u16x4{};
      f32x4 bv = *(const f32x4*)(cb + c0 + c4);
      u16x4 outv;
      #pragma unroll
      for (int c = 0; c < 4; ++c) {
        f32x4 w = *(const f32x4*)(cw + (size_t)(c0 + c4 + c) * 4);
        float a = bv[c] + w[3] * bf2f(t0[c]) + w[2] * bf2f(t1[c])
                        + w[1] * bf2f(t2[c]) + w[0] * bf2f(t3[c]);
        float s = a / (1.f + __expf(-a));
        outv[c] = f2bf(s);
      }
      *(u16x4*)(xcb + (size_t)(m0 + r) * DI_ + c0 + c4) = outv;
      *(u16x4*)(lA + r * 72 + c4) = outv;
    }
    __syncthreads();
    #pragma unroll
    for (int kk = 0; kk < 64; kk += 32) {
      bf16x8 af = *(const bf16x8*)(lA + (wm + fr) * 72 + kk + kg);
      bf16x8 b0 = *(const bf16x8*)(lB + (wn + fr) * 72 + kk + kg);
      bf16x8 b1 = *(const bf16x8*)(lB + (wn + 16 + fr) * 72 + kk + kg);
      acc[0] = __builtin_amdgcn_mfma_f32_16x16x32_bf16(af, b0, acc[0], 0, 0, 0);
      acc[1] = __builtin_amdgcn_mfma_f32_16x16x32_bf16(af, b1, acc[1], 0, 0, 0);
    }
  }
  const int rg = (lane >> 4) * 4;
  #pragma unroll
  for (int j = 0; j < 2; ++j) {
    int col = wn + j * 16 + fr;
    if (col >= 56) continue;
    #pragma unroll
    for (int r = 0; r < 4; ++r) {
      int row = wm + rg + r;
      pbuf[((size_t)ks * M_ + m0 + row) * 56 + col] = acc[j][r];
    }
  }
}

// ---------------- LayerNorm ----------------
__global__ __launch_bounds__(384)
void k_ln(const float* __restrict__ x, const float* __restrict__ g,
          const float* __restrict__ bt, u16* __restrict__ h) {
  const int m = blockIdx.x, d = threadIdx.x;
  __shared__ float red[12];
  float v = x[(size_t)m * D_ + d];
  float s = v, s2 = v * v;
  #pragma unroll
  for (int o = 32; o > 0; o >>= 1) { s += __shfl_xor(s, o); s2 += __shfl_xor(s2, o); }
  int wid = d >> 6;
  if ((d & 63) == 0) { red[wid] = s; red[6 + wid] = s2; }
  __syncthreads();
  float ts = 0.f, ts2 = 0.f;
  #pragma unroll
  for (int w = 0; w < 6; ++w) { ts += red[w]; ts2 += red[6 + w]; }
  float mu = ts / (float)D_;
  float var = ts2 / (float)D_ - mu * mu;
  float rs = rsqrtf(var + 1e-5f);
  h[(size_t)m * D_ + d] = f2bf((v - mu) * rs * g[d] + bt[d]);
}

// ---------------- pass 1: per-segment state only (h_end, scum_end) ----------------
__global__ __launch_bounds__(256)
void k_scan_state(const float* __restrict__ pbuf, const u16* __restrict__ xcb,
                  const float* __restrict__ dtw, const float* __restrict__ dtb,
                  const float* __restrict__ Abuf, float* __restrict__ hend,
                  float* __restrict__ send) {
  const int b   = blockIdx.x;
  const int di0 = blockIdx.y * 64;
  const int s   = blockIdx.z;
  const int tid = threadIdx.x;
  const int dil = tid >> 2, nq = tid & 3;
  const int di  = di0 + dil;
  __shared__ float sDT[SEG][64];
  __shared__ u16   sXC[SEG][64];
  __shared__ float sB [SEG][16];
  __shared__ float sdb[SEG][28];

  const f32x4 Arow = *(const f32x4*)(Abuf + (size_t)di * NST + nq * 4);
  const size_t mb = (size_t)b * L_ + (size_t)s * SEG;
  const int chd = tid & 63;

  {
    int r = tid >> 4, cc = (tid & 15) * 4;
    #pragma unroll
    for (int j = 0; j < 2; ++j) {
      int row = r + j * 16;
      if (row < SEG)
        *(u16x4*)&sXC[row][cc] = *(const u16x4*)(xcb + (mb + row) * DI_ + di0 + cc);
    }
    if (tid < SEG * 6) {
      int row = tid / 6, c4 = (tid % 6) * 4;
      f32x4 ssum = {};
      #pragma unroll
      for (int ks = 0; ks < 4; ++ks)
        ssum += *(const f32x4*)(pbuf + ((size_t)ks * M_ + mb + row) * 56 + c4);
      *(f32x4*)&sdb[row][c4] = ssum;
    }
    if (tid < SEG * 4) {
      int row = tid >> 2, c4 = (tid & 3) * 4;
      f32x4 ssum = {};
      #pragma unroll
      for (int ks = 0; ks < 4; ++ks)
        ssum += *(const f32x4*)(pbuf + ((size_t)ks * M_ + mb + row) * 56 + 24 + c4);
      *(f32x4*)&sB[row][c4] = ssum;
    }
  }
  float w[24];
  #pragma unroll
  for (int r = 0; r < 24; ++r) w[r] = dtw[r * DI_ + di0 + chd];
  const float bvd = dtb[di0 + chd];
  __syncthreads();

  {
    const int rg = tid >> 6;
    #pragma unroll
    for (int rr = 0; rr < 7; ++rr) {
      int row = rg * 7 + rr;
      float acc = bvd;
      #pragma unroll
      for (int r4 = 0; r4 < 6; ++r4) {
        f32x4 sv = *(const f32x4*)&sdb[row][r4 * 4];
        acc += sv[0] * w[r4 * 4] + sv[1] * w[r4 * 4 + 1]
             + sv[2] * w[r4 * 4 + 2] + sv[3] * w[r4 * 4 + 3];
      }
      float e  = __expf(-fabsf(acc));
      sDT[row][chd] = fmaxf(acc, 0.f) + __logf(1.f + e);
    }
  }
  __syncthreads();

  float h[4] = {0.f, 0.f, 0.f, 0.f};
  float scum = 0.f;
  float dtc = sDT[0][dil], xcc = bf2f(sXC[0][dil]);
  f32x4 Bv = *(const f32x4*)&sB[0][nq * 4];
  #pragma unroll 4
  for (int t = 0; t < SEG; ++t) {
    float dtn = 0.f, xcn = 0.f; f32x4 Bn = {};
    if (t + 1 < SEG) {
      dtn = sDT[t + 1][dil]; xcn = bf2f(sXC[t + 1][dil]);
      Bn = *(const f32x4*)&sB[t + 1][nq * 4];
    }
    scum += dtc;
    float dxv = dtc * xcc;
    #pragma unroll
    for (int n = 0; n < 4; ++n) {
      float e = exp2fast(dtc * Arow[n]);
      h[n] = e * h[n] + dxv * Bv[n];
    }
    dtc = dtn; xcc = xcn; Bv = Bn;
  }

  size_t sb = ((size_t)s * B_ + b) * DI_ + di;
  *(f32x4*)(hend + sb * 16 + nq * 4) = f32x4{h[0], h[1], h[2], h[3]};
  if (nq == 0) send[sb] = scum;
}

// ---------------- pass 2: full scan with carry-in + gate -> ybuf ----------------
// sYO stored bf16 (y lands in bf16 ybuf anyway); LDS 17.9 KB -> 8 blocks/CU.
__global__ __launch_bounds__(256)
void k_scan_full(const float* __restrict__ pbuf, const u16* __restrict__ xcb,
                 const u16* __restrict__ xzb, const float* __restrict__ dtw,
                 const float* __restrict__ dtb, const float* __restrict__ Abuf,
                 const float* __restrict__ Dsk, const float* __restrict__ hend,
                 const float* __restrict__ send, u16* __restrict__ yb) {
  const int b   = blockIdx.x;
  const int di0 = blockIdx.y * 64;
  const int s   = blockIdx.z;
  const int tid = threadIdx.x;
  const int dil = tid >> 2, nq = tid & 3;
  const int di  = di0 + dil;
  __shared__ float sDT[SEG][64];
  __shared__ u16   sXC[SEG][64];
  __shared__ float sBC[SEG][32];
  __shared__ __align__(16) u16 sYO[SEG][64];        // bf16 y; pre-scan aliased as sdb
  float (*sdb)[28] = (float(*)[28])&sYO[0][0];      // 3136 B <= 3584 B

  const f32x4 Arow = *(const f32x4*)(Abuf + (size_t)di * NST + nq * 4);
  const float Dv = Dsk[di];
  const size_t mb = (size_t)b * L_ + (size_t)s * SEG;
  const int chd = tid & 63;

  {
    int r = tid >> 4, cc = (tid & 15) * 4;
    #pragma unroll
    for (int j = 0; j < 2; ++j) {
      int row = r + j * 16;
      if (row < SEG)
        *(u16x4*)&sXC[row][cc] = *(const u16x4*)(xcb + (mb + row) * DI_ + di0 + cc);
    }
    if (tid < SEG * 6) {
      int row = tid / 6, c4 = (tid % 6) * 4;
      f32x4 ssum = {};
      #pragma unroll
      for (int ks = 0; ks < 4; ++ks)
        ssum += *(const f32x4*)(pbuf + ((size_t)ks * M_ + mb + row) * 56 + c4);
      *(f32x4*)&sdb[row][c4] = ssum;
    }
    if (tid < SEG * 8) {
      int row = tid >> 3, c4 = (tid & 7) * 4;
      f32x4 ssum = {};
      #pragma unroll
      for (int ks = 0; ks < 4; ++ks)
        ssum += *(const f32x4*)(pbuf + ((size_t)ks * M_ + mb + row) * 56 + 24 + c4);
      *(f32x4*)&sBC[row][c4] = ssum;
    }
  }

  float h[4] = {0.f, 0.f, 0.f, 0.f};
  for (int r = 0; r < s; ++r) {
    size_t sb = ((size_t)r * B_ + b) * DI_ + di;
    f32x4 he = *(const f32x4*)(hend + sb * 16 + nq * 4);
    float se = send[sb];
    #pragma unroll
    for (int q = 0; q < 4; ++q) h[q] = exp2fast(Arow[q] * se) * h[q] + he[q];
  }

  float w[24];
  #pragma unroll
  for (int r = 0; r < 24; ++r) w[r] = dtw[r * DI_ + di0 + chd];
  const float bvd = dtb[di0 + chd];
  __syncthreads();

  {
    const int rg = tid >> 6;
    #pragma unroll
    for (int rr = 0; rr < 7; ++rr) {
      int row = rg * 7 + rr;
      float acc = bvd;
      #pragma unroll
      for (int r4 = 0; r4 < 6; ++r4) {
        f32x4 sv = *(const f32x4*)&sdb[row][r4 * 4];
        acc += sv[0] * w[r4 * 4] + sv[1] * w[r4 * 4 + 1]
             + sv[2] * w[r4 * 4 + 2] + sv[3] * w[r4 * 4 + 3];
      }
      float e  = __expf(-fabsf(acc));
      sDT[row][chd] = fmaxf(acc, 0.f) + __logf(1.f + e);
    }
  }
  __syncthreads();   // sdb dead; sYO writes may begin

  float dtc = sDT[0][dil], xcc = bf2f(sXC[0][dil]);
  f32x4 Bv = *(const f32x4*)&sBC[0][nq * 4];
  f32x4 Cv = *(const f32x4*)&sBC[0][16 + nq * 4];
  #pragma unroll 4
  for (int t = 0; t < SEG; ++t) {
    float dtn = 0.f, xcn = 0.f; f32x4 Bn = {}, Cn = {};
    if (t + 1 < SEG) {
      dtn = sDT[t + 1][dil]; xcn = bf2f(sXC[t + 1][dil]);
      Bn = *(const f32x4*)&sBC[t + 1][nq * 4];
      Cn = *(const f32x4*)&sBC[t + 1][16 + nq * 4];
    }
    float dxv = dtc * xcc;
    float y = 0.f;
    #pragma unroll
    for (int n = 0; n < 4; ++n) {
      float e = exp2fast(dtc * Arow[n]);
      h[n] = e * h[n] + dxv * Bv[n];
      y += h[n] * Cv[n];
    }
    y = quad_sum(y);
    if (nq == 0) sYO[t][dil] = f2bf(y + Dv * xcc);
    dtc = dtn; xcc = xcn; Bv = Bn; Cv = Cn;
  }
  __syncthreads();

  #pragma unroll
  for (int j = 0; j < 4; ++j) {
    int id = tid + j * 256;
    if (id < SEG * 32) {
      int row = id >> 5, c2 = id & 31;
      int ch0 = c2 * 2;
      float y0 = bf2f(sYO[row][ch0]), y1 = bf2f(sYO[row][ch0 + 1]);
      u32 zz = *(const u32*)(xzb + (mb + row) * 1536 + DI_ + di0 + ch0);
      float z0 = bf2f((u16)(zz & 0xffff)), z1 = bf2f((u16)(zz >> 16));
      u32 o = (u32)f2bf(y0 * z0 / (1.f + __expf(-z0)))
            | ((u32)f2bf(y1 * z1 / (1.f + __expf(-z1))) << 16);
      *((u32*)yb + ((mb + row) * DI_ + di0) / 2 + c2) = o;
    }
  }
}

// ---------------- final LN partial sums ----------------
__global__ __launch_bounds__(384)
void k_feat_part(const float* __restrict__ x, float* __restrict__ partial) {
  const int b = blockIdx.x, j = blockIdx.y, d = threadIdx.x;
  __shared__ float red[12];
  const int l0 = j * 28;
  float acc = 0.f;
  float v = x[((size_t)b * L_ + l0) * D_ + d];
  for (int l = l0; l < l0 + 28; ++l) {
    float vn = (l + 1 < l0 + 28) ? x[((size_t)b * L_ + l + 1) * D_ + d] : 0.f;
    float s = v, s2 = v * v;
    #pragma unroll
    for (int o = 32; o > 0; o >>= 1) { s += __shfl_xor(s, o); s2 += __shfl_xor(s2, o); }
    int wid = d >> 6;
    if ((d & 63) == 0) { red[wid] = s; red[6 + wid] = s2; }
    __syncthreads();
    float ts = 0.f, ts2 = 0.f;
    #pragma unroll
    for (int w = 0; w < 6; ++w) { ts += red[w]; ts2 += red[6 + w]; }
    float mu = ts * (1.f / (float)D_);
    float var = ts2 * (1.f / (float)D_) - mu * mu;
    acc += (v - mu) * rsqrtf(var + 1e-5f);
    __syncthreads();
    v = vn;
  }
  partial[((size_t)(b * 7 + j)) * D_ + d] = acc;
}

// ---------------- head ----------------
__global__ __launch_bounds__(256)
void k_head(const float* __restrict__ partial, const float* __restrict__ g,
            const float* __restrict__ bt, const float* __restrict__ hw,
            const float* __restrict__ hb, float* __restrict__ out) {
  const int b = blockIdx.y;
  const int c = blockIdx.x * 256 + threadIdx.x;
  __shared__ float sf[D_];
  for (int i = threadIdx.x; i < D_; i += 256) {
    float s = 0.f;
    #pragma unroll
    for (int j = 0; j < 7; ++j) s += partial[((size_t)(b * 7 + j)) * D_ + i];
    sf[i] = g[i] * (s * (1.f / (float)L_)) + bt[i];
  }
  __syncthreads();
  if (c >= NC_) return;
  float acc = hb[c];
  for (int d = 0; d < D_; ++d) acc += sf[d] * hw[(size_t)d * NC_ + c];
  out[(size_t)b * NC_ + c] = acc;
}

// =====================================================================
extern "C" void kernel_launch(void* const* d_in, const int* in_sizes, int n_in,
                              void* d_out, int out_size, void* d_ws, size_t ws_size,
                              hipStream_t stream) {
  const float* x_in    = (const float*)d_in[0];
  const float* patch_w = (const float*)d_in[1];
  const float* patch_b = (const float*)d_in[2];
  const float* pos     = (const float*)d_in[3];
  const float* bn_g    = (const float*)d_in[4];
  const float* bn_b    = (const float*)d_in[5];
  const float* in_w    = (const float*)d_in[6];
  const float* conv_w  = (const float*)d_in[7];
  const float* conv_b  = (const float*)d_in[8];
  const float* xp_w    = (const float*)d_in[9];
  const float* dtp_w   = (const float*)d_in[10];
  const float* dtp_b   = (const float*)d_in[11];
  const float* A_log   = (const float*)d_in[12];
  const float* D_skip  = (const float*)d_in[13];
  const float* out_w   = (const float*)d_in[14];
  const float* norm_g  = (const float*)d_in[15];
  const float* norm_b  = (const float*)d_in[16];
  const float* head_w  = (const float*)d_in[17];
  const float* head_b  = (const float*)d_in[18];
  float* out = (float*)d_out;

  char* ws = (char*)d_ws;
  size_t off = 0;
  auto alloc = [&](size_t bytes) { size_t o = off; off += (bytes + 255) & ~(size_t)255; return o; };

  float* xbuf   = (float*)(ws + alloc((size_t)M_ * D_ * 4));
  u16*   hbuf   = (u16*)  (ws + alloc((size_t)M_ * D_ * 2));
  u16*   xzb    = (u16*)  (ws + alloc((size_t)M_ * 1536 * 2));
  u16*   xcbb   = (u16*)  (ws + alloc((size_t)M_ * DI_ * 2));
  float* pbuf   = (float*)(ws + alloc((size_t)4 * M_ * 56 * 4));
  u16*   im2col = (u16*)  (ws + alloc((size_t)M_ * 768 * 2));
  u16*   ybuf   = (u16*)  (ws + alloc((size_t)M_ * DI_ * 2));
  float* hend   = (float*)(ws + alloc((size_t)NSEG * B_ * DI_ * NST * 4));
  float* send   = (float*)(ws + alloc((size_t)NSEG * B_ * DI_ * 4));
  float* Abuf   = (float*)(ws + alloc((size_t)DEPTH * DI_ * NST * 4));
  float* partial= (float*)(ws + alloc((size_t)B_ * 7 * D_ * 4));
  u16*   in_wT  = (u16*)  (ws + alloc((size_t)DEPTH * 1536 * D_ * 2));
  u16*   xp_wT  = (u16*)  (ws + alloc((size_t)DEPTH * 56 * DI_ * 2));
  u16*   out_wT = (u16*)  (ws + alloc((size_t)DEPTH * D_ * DI_ * 2));
  u16*   pw_b   = (u16*)  (ws + alloc((size_t)D_ * 768 * 2));

  dim3 tb(32, 8);
  k_transpose_bf16<<<dim3(48, 12, DEPTH), tb, 0, stream>>>(in_w,  in_wT,  D_, 1536);
  k_transpose_bf16<<<dim3(2, 24, DEPTH),  tb, 0, stream>>>(xp_w,  xp_wT,  DI_, 56);
  k_transpose_bf16<<<dim3(12, 24, DEPTH), tb, 0, stream>>>(out_w, out_wT, DI_, D_);
  k_convert_bf16<<<(D_ * 768 + 255) / 256, 256, 0, stream>>>(patch_w, pw_b, D_ * 768);
  k_prepA<<<(DEPTH * DI_ * NST + 255) / 256, 256, 0, stream>>>(A_log, Abuf, DEPTH * DI_ * NST);

  k_im2col<<<(M_ * 768 + 255) / 256, 256, 0, stream>>>(x_in, im2col);
  k_gemm<64,64,2,0><<<dim3(M_ / 64, 6), 256, 0, stream>>>(im2col, pw_b, xbuf, D_, 768, patch_b, pos);

  for (int dp = 0; dp < DEPTH; ++dp) {
    const u16* iwt = in_wT  + (size_t)dp * 1536 * D_;
    const u16* xwt = xp_wT  + (size_t)dp * 56 * DI_;
    const u16* owt = out_wT + (size_t)dp * D_ * DI_;
    const float* Al = Abuf + (size_t)dp * DI_ * NST;
    const float* dw = dtp_w + (size_t)dp * R_ * DI_;
    const float* db = dtp_b + dp * DI_;
    k_ln<<<M_, 384, 0, stream>>>(xbuf, bn_g + dp * D_, bn_b + dp * D_, hbuf);
    k_gemm<128,128,0,1><<<dim3(M_ / 128, 12), 256, 0, stream>>>(hbuf, iwt, (float*)xzb, 1536, D_, nullptr, nullptr);
    k_xp_conv<<<dim3(M_ / 32, 4), 256, 0, stream>>>(xzb, conv_w + (size_t)dp * DI_ * 4,
                                                    conv_b + dp * DI_, xwt, xcbb, pbuf);
    k_scan_state<<<dim3(B_, DI_ / 64, NSEG - 1), 256, 0, stream>>>(pbuf, xcbb, dw, db, Al,
                                                                   hend, send);
    k_scan_full<<<dim3(B_, DI_ / 64, NSEG), 256, 0, stream>>>(pbuf, xcbb, xzb, dw, db, Al,
                                                              D_skip + dp * DI_, hend, send, ybuf);
    k_gemm<64,64,1,0><<<dim3(M_ / 64, 6), 256, 0, stream>>>(ybuf, owt, xbuf, D_, DI_, nullptr, nullptr);
  }

  k_feat_part<<<dim3(B_, 7), 384, 0, stream>>>(xbuf, partial);
  k_head<<<dim3((NC_ + 255) / 256, B_), 256, 0, stream>>>(partial, norm_g, norm_b, head_w, head_b, out);
}

// Round 16
// 1331.456 us; speedup vs baseline: 1.0297x; 1.0297x over previous
//
#include <hip/hip_runtime.h>
#include <math.h>

typedef short bf16x8 __attribute__((ext_vector_type(8)));
typedef float f32x4 __attribute__((ext_vector_type(4)));
typedef float f32x2 __attribute__((ext_vector_type(2)));
typedef unsigned short u16;
typedef unsigned int u32;
typedef unsigned short u16x4 __attribute__((ext_vector_type(4)));

#define B_    32
#define D_    384
#define DEPTH 12
#define NST   16
#define DI_   768
#define R_    24
#define L_    196
#define NC_   1000
#define M_    (B_*L_)   // 6272
#define SEG   28
#define NSEG  7

__device__ __forceinline__ u16 f2bf(float f) {
  union { float f; unsigned u; } v; v.f = f;
  unsigned r = v.u + 0x7fffu + ((v.u >> 16) & 1u);
  return (u16)(r >> 16);
}
__device__ __forceinline__ float bf2f(u16 x) {
  union { unsigned u; float f; } v; v.u = ((unsigned)x) << 16;
  return v.f;
}
__device__ __forceinline__ float quad_sum(float y) {
  y += __int_as_float(__builtin_amdgcn_update_dpp(0, __float_as_int(y), 0xB1, 0xf, 0xf, true));
  y += __int_as_float(__builtin_amdgcn_update_dpp(0, __float_as_int(y), 0x4E, 0xf, 0xf, true));
  return y;
}
__device__ __forceinline__ float exp2fast(float x) {
  return __builtin_amdgcn_exp2f(x);
}

// ---------------- weight prep ----------------
__global__ void k_transpose_bf16(const float* __restrict__ in, u16* __restrict__ out,
                                 int R, int C) {
  __shared__ float tile[32][33];
  const size_t zoff = (size_t)blockIdx.z * R * C;
  in  += zoff; out += zoff;
  int c0 = blockIdx.x * 32, r0 = blockIdx.y * 32;
  int tx = threadIdx.x, ty = threadIdx.y;
  for (int i = ty; i < 32; i += 8) {
    int r = r0 + i, c = c0 + tx;
    tile[i][tx] = (r < R && c < C) ? in[(size_t)r * C + c] : 0.f;
  }
  __syncthreads();
  for (int i = ty; i < 32; i += 8) {
    int c = c0 + i, r = r0 + tx;
    if (c < C && r < R) out[(size_t)c * R + r] = f2bf(tile[tx][i]);
  }
}

__global__ void k_convert_bf16(const float* __restrict__ in, u16* __restrict__ out, int n) {
  int i = blockIdx.x * 256 + threadIdx.x;
  if (i < n) out[i] = f2bf(in[i]);
}

// A2 = -exp(A_log) * log2(e)
__global__ void k_prepA(const float* __restrict__ alog, float* __restrict__ A, int n) {
  int i = blockIdx.x * 256 + threadIdx.x;
  if (i < n) A[i] = -__expf(alog[i]) * 1.44269504088896340736f;
}

// ---------------- im2col ----------------
__global__ void k_im2col(const float* __restrict__ x, u16* __restrict__ xcol) {
  int idx = blockIdx.x * 256 + threadIdx.x;
  if (idx >= M_ * 768) return;
  int k = idx % 768, m = idx / 768;
  int b = m / L_, l = m % L_;
  int li = l / 14, lj = l % 14;
  int c = k / 256, r = k % 256;
  int i = r / 16, j = r % 16;
  int hh = li * 16 + i, ww = lj * 16 + j;
  xcol[idx] = f2bf(x[(((size_t)b * 3 + c) * 224 + hh) * 224 + ww]);
}

// ---------------- GEMM (software-pipelined) ----------------
template<int BM, int BN, int EPI, int OB>
__global__ __launch_bounds__(256)
void k_gemm(const u16* __restrict__ A, const u16* __restrict__ BT,
            float* __restrict__ Cout, int Nn, int Kk,
            const float* __restrict__ bias, const float* __restrict__ pos) {
  const int m0 = blockIdx.x * BM;
  const int n0 = blockIdx.y * BN;
  __shared__ u16 lA[BM * 72];
  __shared__ u16 lB[BN * 72];
  const int tid  = threadIdx.x;
  const int wave = tid >> 6, lane = tid & 63;
  const int wm = (wave >> 1) * (BM / 2), wn = (wave & 1) * (BN / 2);
  constexpr int MI = BM / 32, NJ = BN / 32;
  constexpr int NV = (BM + BN) / 32;
  f32x4 acc[MI][NJ] = {};
  const int fr = lane & 15, kg = (lane >> 4) * 8;

  bf16x8 v[NV];
  auto load = [&](int k0) {
    #pragma unroll
    for (int q = 0; q < NV; ++q) {
      int id = tid + q * 256;
      int row = id >> 3, vv = id & 7;
      bf16x8 t = {};
      if (row < BM) {
        t = *(const bf16x8*)(A + (size_t)(m0 + row) * Kk + k0 + vv * 8);
      } else {
        int br = n0 + row - BM;
        if (br < Nn) t = *(const bf16x8*)(BT + (size_t)br * Kk + k0 + vv * 8);
      }
      v[q] = t;
    }
  };
  load(0);
  for (int k0 = 0; k0 < Kk; k0 += 64) {
    __syncthreads();
    #pragma unroll
    for (int q = 0; q < NV; ++q) {
      int id = tid + q * 256;
      int row = id >> 3, vv = id & 7;
      u16* dst = (row < BM) ? (lA + row * 72 + vv * 8) : (lB + (size_t)(row - BM) * 72 + vv * 8);
      *(bf16x8*)dst = v[q];
    }
    __syncthreads();
    if (k0 + 64 < Kk) load(k0 + 64);
    #pragma unroll
    for (int kk = 0; kk < 64; kk += 32) {
      bf16x8 af[MI], bfr[NJ];
      #pragma unroll
      for (int i = 0; i < MI; ++i)
        af[i] = *(const bf16x8*)(lA + (wm + i * 16 + fr) * 72 + kk + kg);
      #pragma unroll
      for (int j = 0; j < NJ; ++j)
        bfr[j] = *(const bf16x8*)(lB + (wn + j * 16 + fr) * 72 + kk + kg);
      #pragma unroll
      for (int i = 0; i < MI; ++i)
        #pragma unroll
        for (int j = 0; j < NJ; ++j)
          acc[i][j] = __builtin_amdgcn_mfma_f32_16x16x32_bf16(af[i], bfr[j], acc[i][j], 0, 0, 0);
    }
  }

  const int rg = (lane >> 4) * 4;
  #pragma unroll
  for (int i = 0; i < MI; ++i) {
    int row = m0 + wm + i * 16 + rg;
    #pragma unroll
    for (int j = 0; j < NJ; ++j) {
      int col = n0 + wn + j * 16 + fr;
      if (col >= Nn) continue;
      #pragma unroll
      for (int r = 0; r < 4; ++r) {
        float vv = acc[i][j][r];
        size_t idx = (size_t)(row + r) * Nn + col;
        if (EPI == 0) {
          if (OB) ((u16*)Cout)[idx] = f2bf(vv);
          else    Cout[idx] = vv;
        }
        else if (EPI == 1) Cout[idx] += vv;
        else               Cout[idx] = vv + bias[col] + pos[(size_t)((row + r) % L_) * Nn + col];
      }
    }
  }
}

// ---------------- fused conv+SiLU + xp skinny GEMM (K-split x4) ----------------
__global__ __launch_bounds__(256)
void k_xp_conv(const u16* __restrict__ xzb, const float* __restrict__ cw,
               const float* __restrict__ cb, const u16* __restrict__ BT,
               u16* __restrict__ xcb, float* __restrict__ pbuf) {
  const int m0  = blockIdx.x * 32;
  const int ks  = blockIdx.y;
  const int ch0 = ks * 192;
  __shared__ u16 sXZ[35][64];
  __shared__ u16 lA[32 * 72];
  __shared__ u16 lB[64 * 72];
  const int tid  = threadIdx.x;
  const int wave = tid >> 6, lane = tid & 63;
  const int wm = (wave >> 1) * 16, wn = (wave & 1) * 32;
  const int fr = lane & 15, kg = (lane >> 4) * 8;
  f32x4 acc[2] = {};

  for (int kc = 0; kc < 3; ++kc) {
    const int c0 = ch0 + kc * 64;
    __syncthreads();
    #pragma unroll
    for (int j = 0; j < 2; ++j) {
      int u = tid + j * 256;
      if (u < 448) {
        int row = u >> 3, vv = u & 7;
        *(bf16x8*)(lB + row * 72 + vv * 8) =
            *(const bf16x8*)(BT + (size_t)row * DI_ + c0 + vv * 8);
      }
    }
    #pragma unroll
    for (int j = 0; j < 3; ++j) {
      int u = tid + j * 256;
      if (u < 560) {
        int row = u >> 4, c4 = (u & 15) * 4;
        int gm = m0 - 3 + row; if (gm < 0) gm = 0;
        *(u16x4*)&sXZ[row][c4] = *(const u16x4*)(xzb + (size_t)gm * 1536 + c0 + c4);
      }
    }
    __syncthreads();
    #pragma unroll
    for (int j = 0; j < 2; ++j) {
      int g = tid + j * 256;
      int r = g >> 4, c4 = (g & 15) * 4;
      int l = (m0 + r) % L_;
      u16x4 t0 = *(const u16x4*)&sXZ[r + 3][c4];
      u16x4 t1 = (l >= 1) ? *(const u16x4*)&sXZ[r + 2][c4] : u16x4{};
      u16x4 t2 = (l >= 2) ? *(const u16x4*)&sXZ[r + 1][c4] : u16x4{};
      u16x4 t3 = (l >= 3) ? *(const u16x4*)&sXZ[r    ][c4] : u16x4{};
      f32x4 bv = *(const f32x4*)(cb + c0 + c4);
      u16x4 outv;
      #pragma unroll
      for (int c = 0; c < 4; ++c) {
        f32x4 w = *(const f32x4*)(cw + (size_t)(c0 + c4 + c) * 4);
        float a = bv[c] + w[3] * bf2f(t0[c]) + w[2] * bf2f(t1[c])
                        + w[1] * bf2f(t2[c]) + w[0] * bf2f(t3[c]);
        float s = a / (1.f + __expf(-a));
        outv[c] = f2bf(s);
      }
      *(u16x4*)(xcb + (size_t)(m0 + r) * DI_ + c0 + c4) = outv;
      *(u16x4*)(lA + r * 72 + c4) = outv;
    }
    __syncthreads();
    #pragma unroll
    for (int kk = 0; kk < 64; kk += 32) {
      bf16x8 af = *(const bf16x8*)(lA + (wm + fr) * 72 + kk + kg);
      bf16x8 b0 = *(const bf16x8*)(lB + (wn + fr) * 72 + kk + kg);
      bf16x8 b1 = *(const bf16x8*)(lB + (wn + 16 + fr) * 72 + kk + kg);
      acc[0] = __builtin_amdgcn_mfma_f32_16x16x32_bf16(af, b0, acc[0], 0, 0, 0);
      acc[1] = __builtin_amdgcn_mfma_f32_16x16x32_bf16(af, b1, acc[1], 0, 0, 0);
    }
  }
  const int rg = (lane >> 4) * 4;
  #pragma unroll
  for (int j = 0; j < 2; ++j) {
    int col = wn + j * 16 + fr;
    if (col >= 56) continue;
    #pragma unroll
    for (int r = 0; r < 4; ++r) {
      int row = wm + rg + r;
      pbuf[((size_t)ks * M_ + m0 + row) * 56 + col] = acc[j][r];
    }
  }
}

// ---------------- LayerNorm ----------------
__global__ __launch_bounds__(384)
void k_ln(const float* __restrict__ x, const float* __restrict__ g,
          const float* __restrict__ bt, u16* __restrict__ h) {
  const int m = blockIdx.x, d = threadIdx.x;
  __shared__ float red[12];
  float v = x[(size_t)m * D_ + d];
  float s = v, s2 = v * v;
  #pragma unroll
  for (int o = 32; o > 0; o >>= 1) { s += __shfl_xor(s, o); s2 += __shfl_xor(s2, o); }
  int wid = d >> 6;
  if ((d & 63) == 0) { red[wid] = s; red[6 + wid] = s2; }
  __syncthreads();
  float ts = 0.f, ts2 = 0.f;
  #pragma unroll
  for (int w = 0; w < 6; ++w) { ts += red[w]; ts2 += red[6 + w]; }
  float mu = ts / (float)D_;
  float var = ts2 / (float)D_ - mu * mu;
  float rs = rsqrtf(var + 1e-5f);
  h[(size_t)m * D_ + d] = f2bf((v - mu) * rs * g[d] + bt[d]);
}

// ---------------- pass 1: per-segment state only (h_end, scum_end) ----------------
__global__ __launch_bounds__(256)
void k_scan_state(const float* __restrict__ pbuf, const u16* __restrict__ xcb,
                  const float* __restrict__ dtw, const float* __restrict__ dtb,
                  const float* __restrict__ Abuf, float* __restrict__ hend,
                  float* __restrict__ send) {
  const int b   = blockIdx.x;
  const int di0 = blockIdx.y * 64;
  const int s   = blockIdx.z;
  const int tid = threadIdx.x;
  const int dil = tid >> 2, nq = tid & 3;
  const int di  = di0 + dil;
  __shared__ float sDT[SEG][64];
  __shared__ u16   sXC[SEG][64];
  __shared__ float sB [SEG][16];
  __shared__ float sdb[SEG][28];

  const f32x4 Arow = *(const f32x4*)(Abuf + (size_t)di * NST + nq * 4);
  const size_t mb = (size_t)b * L_ + (size_t)s * SEG;
  const int chd = tid & 63;

  {
    int r = tid >> 4, cc = (tid & 15) * 4;
    #pragma unroll
    for (int j = 0; j < 2; ++j) {
      int row = r + j * 16;
      if (row < SEG)
        *(u16x4*)&sXC[row][cc] = *(const u16x4*)(xcb + (mb + row) * DI_ + di0 + cc);
    }
    if (tid < SEG * 6) {
      int row = tid / 6, c4 = (tid % 6) * 4;
      f32x4 ssum = {};
      #pragma unroll
      for (int ks = 0; ks < 4; ++ks)
        ssum += *(const f32x4*)(pbuf + ((size_t)ks * M_ + mb + row) * 56 + c4);
      *(f32x4*)&sdb[row][c4] = ssum;
    }
    if (tid < SEG * 4) {
      int row = tid >> 2, c4 = (tid & 3) * 4;
      f32x4 ssum = {};
      #pragma unroll
      for (int ks = 0; ks < 4; ++ks)
        ssum += *(const f32x4*)(pbuf + ((size_t)ks * M_ + mb + row) * 56 + 24 + c4);
      *(f32x4*)&sB[row][c4] = ssum;
    }
  }
  float w[24];
  #pragma unroll
  for (int r = 0; r < 24; ++r) w[r] = dtw[r * DI_ + di0 + chd];
  const float bvd = dtb[di0 + chd];
  __syncthreads();

  {
    const int rg = tid >> 6;
    #pragma unroll
    for (int rr = 0; rr < 7; ++rr) {
      int row = rg * 7 + rr;
      float acc = bvd;
      #pragma unroll
      for (int r4 = 0; r4 < 6; ++r4) {
        f32x4 sv = *(const f32x4*)&sdb[row][r4 * 4];
        acc += sv[0] * w[r4 * 4] + sv[1] * w[r4 * 4 + 1]
             + sv[2] * w[r4 * 4 + 2] + sv[3] * w[r4 * 4 + 3];
      }
      float e  = __expf(-fabsf(acc));
      sDT[row][chd] = fmaxf(acc, 0.f) + __logf(1.f + e);
    }
  }
  __syncthreads();

  float h[4] = {0.f, 0.f, 0.f, 0.f};
  float scum = 0.f;
  float dtc = sDT[0][dil], xcc = bf2f(sXC[0][dil]);
  f32x4 Bv = *(const f32x4*)&sB[0][nq * 4];
  #pragma unroll 4
  for (int t = 0; t < SEG; ++t) {
    float dtn = 0.f, xcn = 0.f; f32x4 Bn = {};
    if (t + 1 < SEG) {
      dtn = sDT[t + 1][dil]; xcn = bf2f(sXC[t + 1][dil]);
      Bn = *(const f32x4*)&sB[t + 1][nq * 4];
    }
    scum += dtc;
    float dxv = dtc * xcc;
    #pragma unroll
    for (int n = 0; n < 4; ++n) {
      float e = exp2fast(dtc * Arow[n]);
      h[n] = e * h[n] + dxv * Bv[n];
    }
    dtc = dtn; xcc = xcn; Bv = Bn;
  }

  size_t sb = ((size_t)s * B_ + b) * DI_ + di;
  *(f32x4*)(hend + sb * 16 + nq * 4) = f32x4{h[0], h[1], h[2], h[3]};
  if (nq == 0) send[sb] = scum;
}

// ---------------- pass 2: full scan with carry-in + gate -> ybuf ----------------
// sYO stored bf16; LDS 17.9 KB -> 8 blocks/CU.
__global__ __launch_bounds__(256)
void k_scan_full(const float* __restrict__ pbuf, const u16* __restrict__ xcb,
                 const u16* __restrict__ xzb, const float* __restrict__ dtw,
                 const float* __restrict__ dtb, const float* __restrict__ Abuf,
                 const float* __restrict__ Dsk, const float* __restrict__ hend,
                 const float* __restrict__ send, u16* __restrict__ yb) {
  const int b   = blockIdx.x;
  const int di0 = blockIdx.y * 64;
  const int s   = blockIdx.z;
  const int tid = threadIdx.x;
  const int dil = tid >> 2, nq = tid & 3;
  const int di  = di0 + dil;
  __shared__ float sDT[SEG][64];
  __shared__ u16   sXC[SEG][64];
  __shared__ float sBC[SEG][32];
  __shared__ __align__(16) u16 sYO[SEG][64];        // bf16 y; pre-scan aliased as sdb
  float (*sdb)[28] = (float(*)[28])&sYO[0][0];      // 3136 B <= 3584 B

  const f32x4 Arow = *(const f32x4*)(Abuf + (size_t)di * NST + nq * 4);
  const float Dv = Dsk[di];
  const size_t mb = (size_t)b * L_ + (size_t)s * SEG;
  const int chd = tid & 63;

  {
    int r = tid >> 4, cc = (tid & 15) * 4;
    #pragma unroll
    for (int j = 0; j < 2; ++j) {
      int row = r + j * 16;
      if (row < SEG)
        *(u16x4*)&sXC[row][cc] = *(const u16x4*)(xcb + (mb + row) * DI_ + di0 + cc);
    }
    if (tid < SEG * 6) {
      int row = tid / 6, c4 = (tid % 6) * 4;
      f32x4 ssum = {};
      #pragma unroll
      for (int ks = 0; ks < 4; ++ks)
        ssum += *(const f32x4*)(pbuf + ((size_t)ks * M_ + mb + row) * 56 + c4);
      *(f32x4*)&sdb[row][c4] = ssum;
    }
    if (tid < SEG * 8) {
      int row = tid >> 3, c4 = (tid & 7) * 4;
      f32x4 ssum = {};
      #pragma unroll
      for (int ks = 0; ks < 4; ++ks)
        ssum += *(const f32x4*)(pbuf + ((size_t)ks * M_ + mb + row) * 56 + 24 + c4);
      *(f32x4*)&sBC[row][c4] = ssum;
    }
  }

  float h[4] = {0.f, 0.f, 0.f, 0.f};
  for (int r = 0; r < s; ++r) {
    size_t sb = ((size_t)r * B_ + b) * DI_ + di;
    f32x4 he = *(const f32x4*)(hend + sb * 16 + nq * 4);
    float se = send[sb];
    #pragma unroll
    for (int q = 0; q < 4; ++q) h[q] = exp2fast(Arow[q] * se) * h[q] + he[q];
  }

  float w[24];
  #pragma unroll
  for (int r = 0; r < 24; ++r) w[r] = dtw[r * DI_ + di0 + chd];
  const float bvd = dtb[di0 + chd];
  __syncthreads();

  {
    const int rg = tid >> 6;
    #pragma unroll
    for (int rr = 0; rr < 7; ++rr) {
      int row = rg * 7 + rr;
      float acc = bvd;
      #pragma unroll
      for (int r4 = 0; r4 < 6; ++r4) {
        f32x4 sv = *(const f32x4*)&sdb[row][r4 * 4];
        acc += sv[0] * w[r4 * 4] + sv[1] * w[r4 * 4 + 1]
             + sv[2] * w[r4 * 4 + 2] + sv[3] * w[r4 * 4 + 3];
      }
      float e  = __expf(-fabsf(acc));
      sDT[row][chd] = fmaxf(acc, 0.f) + __logf(1.f + e);
    }
  }
  __syncthreads();   // sdb dead; sYO writes may begin

  float dtc = sDT[0][dil], xcc = bf2f(sXC[0][dil]);
  f32x4 Bv = *(const f32x4*)&sBC[0][nq * 4];
  f32x4 Cv = *(const f32x4*)&sBC[0][16 + nq * 4];
  #pragma unroll 4
  for (int t = 0; t < SEG; ++t) {
    float dtn = 0.f, xcn = 0.f; f32x4 Bn = {}, Cn = {};
    if (t + 1 < SEG) {
      dtn = sDT[t + 1][dil]; xcn = bf2f(sXC[t + 1][dil]);
      Bn = *(const f32x4*)&sBC[t + 1][nq * 4];
      Cn = *(const f32x4*)&sBC[t + 1][16 + nq * 4];
    }
    float dxv = dtc * xcc;
    float y = 0.f;
    #pragma unroll
    for (int n = 0; n < 4; ++n) {
      float e = exp2fast(dtc * Arow[n]);
      h[n] = e * h[n] + dxv * Bv[n];
      y += h[n] * Cv[n];
    }
    y = quad_sum(y);
    if (nq == 0) sYO[t][dil] = f2bf(y + Dv * xcc);
    dtc = dtn; xcc = xcn; Bv = Bn; Cv = Cn;
  }
  __syncthreads();

  #pragma unroll
  for (int j = 0; j < 4; ++j) {
    int id = tid + j * 256;
    if (id < SEG * 32) {
      int row = id >> 5, c2 = id & 31;
      int ch0 = c2 * 2;
      float y0 = bf2f(sYO[row][ch0]), y1 = bf2f(sYO[row][ch0 + 1]);
      u32 zz = *(const u32*)(xzb + (mb + row) * 1536 + DI_ + di0 + ch0);
      float z0 = bf2f((u16)(zz & 0xffff)), z1 = bf2f((u16)(zz >> 16));
      u32 o = (u32)f2bf(y0 * z0 / (1.f + __expf(-z0)))
            | ((u32)f2bf(y1 * z1 / (1.f + __expf(-z1))) << 16);
      *((u32*)yb + ((mb + row) * DI_ + di0) / 2 + c2) = o;
    }
  }
}

// ---------------- final LN partial sums ----------------
__global__ __launch_bounds__(384)
void k_feat_part(const float* __restrict__ x, float* __restrict__ partial) {
  const int b = blockIdx.x, j = blockIdx.y, d = threadIdx.x;
  __shared__ float red[12];
  const int l0 = j * 28;
  float acc = 0.f;
  float v = x[((size_t)b * L_ + l0) * D_ + d];
  for (int l = l0; l < l0 + 28; ++l) {
    float vn = (l + 1 < l0 + 28) ? x[((size_t)b * L_ + l + 1) * D_ + d] : 0.f;
    float s = v, s2 = v * v;
    #pragma unroll
    for (int o = 32; o > 0; o >>= 1) { s += __shfl_xor(s, o); s2 += __shfl_xor(s2, o); }
    int wid = d >> 6;
    if ((d & 63) == 0) { red[wid] = s; red[6 + wid] = s2; }
    __syncthreads();
    float ts = 0.f, ts2 = 0.f;
    #pragma unroll
    for (int w = 0; w < 6; ++w) { ts += red[w]; ts2 += red[6 + w]; }
    float mu = ts * (1.f / (float)D_);
    float var = ts2 * (1.f / (float)D_) - mu * mu;
    acc += (v - mu) * rsqrtf(var + 1e-5f);
    __syncthreads();
    v = vn;
  }
  partial[((size_t)(b * 7 + j)) * D_ + d] = acc;
}

// ---------------- head ----------------
__global__ __launch_bounds__(256)
void k_head(const float* __restrict__ partial, const float* __restrict__ g,
            const float* __restrict__ bt, const float* __restrict__ hw,
            const float* __restrict__ hb, float* __restrict__ out) {
  const int b = blockIdx.y;
  const int c = blockIdx.x * 256 + threadIdx.x;
  __shared__ float sf[D_];
  for (int i = threadIdx.x; i < D_; i += 256) {
    float s = 0.f;
    #pragma unroll
    for (int j = 0; j < 7; ++j) s += partial[((size_t)(b * 7 + j)) * D_ + i];
    sf[i] = g[i] * (s * (1.f / (float)L_)) + bt[i];
  }
  __syncthreads();
  if (c >= NC_) return;
  float acc = hb[c];
  for (int d = 0; d < D_; ++d) acc += sf[d] * hw[(size_t)d * NC_ + c];
  out[(size_t)b * NC_ + c] = acc;
}

// =====================================================================
extern "C" void kernel_launch(void* const* d_in, const int* in_sizes, int n_in,
                              void* d_out, int out_size, void* d_ws, size_t ws_size,
                              hipStream_t stream) {
  const float* x_in    = (const float*)d_in[0];
  const float* patch_w = (const float*)d_in[1];
  const float* patch_b = (const float*)d_in[2];
  const float* pos     = (const float*)d_in[3];
  const float* bn_g    = (const float*)d_in[4];
  const float* bn_b    = (const float*)d_in[5];
  const float* in_w    = (const float*)d_in[6];
  const float* conv_w  = (const float*)d_in[7];
  const float* conv_b  = (const float*)d_in[8];
  const float* xp_w    = (const float*)d_in[9];
  const float* dtp_w   = (const float*)d_in[10];
  const float* dtp_b   = (const float*)d_in[11];
  const float* A_log   = (const float*)d_in[12];
  const float* D_skip  = (const float*)d_in[13];
  const float* out_w   = (const float*)d_in[14];
  const float* norm_g  = (const float*)d_in[15];
  const float* norm_b  = (const float*)d_in[16];
  const float* head_w  = (const float*)d_in[17];
  const float* head_b  = (const float*)d_in[18];
  float* out = (float*)d_out;

  char* ws = (char*)d_ws;
  size_t off = 0;
  auto alloc = [&](size_t bytes) { size_t o = off; off += (bytes + 255) & ~(size_t)255; return o; };

  float* xbuf   = (float*)(ws + alloc((size_t)M_ * D_ * 4));
  u16*   hbuf   = (u16*)  (ws + alloc((size_t)M_ * D_ * 2));
  u16*   xzb    = (u16*)  (ws + alloc((size_t)M_ * 1536 * 2));
  u16*   xcbb   = (u16*)  (ws + alloc((size_t)M_ * DI_ * 2));
  float* pbuf   = (float*)(ws + alloc((size_t)4 * M_ * 56 * 4));
  u16*   im2col = (u16*)  (ws + alloc((size_t)M_ * 768 * 2));
  u16*   ybuf   = (u16*)  (ws + alloc((size_t)M_ * DI_ * 2));
  float* hend   = (float*)(ws + alloc((size_t)NSEG * B_ * DI_ * NST * 4));
  float* send   = (float*)(ws + alloc((size_t)NSEG * B_ * DI_ * 4));
  float* Abuf   = (float*)(ws + alloc((size_t)DEPTH * DI_ * NST * 4));
  float* partial= (float*)(ws + alloc((size_t)B_ * 7 * D_ * 4));
  u16*   in_wT  = (u16*)  (ws + alloc((size_t)DEPTH * 1536 * D_ * 2));
  u16*   xp_wT  = (u16*)  (ws + alloc((size_t)DEPTH * 56 * DI_ * 2));
  u16*   out_wT = (u16*)  (ws + alloc((size_t)DEPTH * D_ * DI_ * 2));
  u16*   pw_b   = (u16*)  (ws + alloc((size_t)D_ * 768 * 2));

  dim3 tb(32, 8);
  k_transpose_bf16<<<dim3(48, 12, DEPTH), tb, 0, stream>>>(in_w,  in_wT,  D_, 1536);
  k_transpose_bf16<<<dim3(2, 24, DEPTH),  tb, 0, stream>>>(xp_w,  xp_wT,  DI_, 56);
  k_transpose_bf16<<<dim3(12, 24, DEPTH), tb, 0, stream>>>(out_w, out_wT, DI_, D_);
  k_convert_bf16<<<(D_ * 768 + 255) / 256, 256, 0, stream>>>(patch_w, pw_b, D_ * 768);
  k_prepA<<<(DEPTH * DI_ * NST + 255) / 256, 256, 0, stream>>>(A_log, Abuf, DEPTH * DI_ * NST);

  k_im2col<<<(M_ * 768 + 255) / 256, 256, 0, stream>>>(x_in, im2col);
  k_gemm<64,64,2,0><<<dim3(M_ / 64, 6), 256, 0, stream>>>(im2col, pw_b, xbuf, D_, 768, patch_b, pos);

  for (int dp = 0; dp < DEPTH; ++dp) {
    const u16* iwt = in_wT  + (size_t)dp * 1536 * D_;
    const u16* xwt = xp_wT  + (size_t)dp * 56 * DI_;
    const u16* owt = out_wT + (size_t)dp * D_ * DI_;
    const float* Al = Abuf + (size_t)dp * DI_ * NST;
    const float* dw = dtp_w + (size_t)dp * R_ * DI_;
    const float* db = dtp_b + dp * DI_;
    k_ln<<<M_, 384, 0, stream>>>(xbuf, bn_g + dp * D_, bn_b + dp * D_, hbuf);
    k_gemm<64,128,0,1><<<dim3(M_ / 64, 12), 256, 0, stream>>>(hbuf, iwt, (float*)xzb, 1536, D_, nullptr, nullptr);
    k_xp_conv<<<dim3(M_ / 32, 4), 256, 0, stream>>>(xzb, conv_w + (size_t)dp * DI_ * 4,
                                                    conv_b + dp * DI_, xwt, xcbb, pbuf);
    k_scan_state<<<dim3(B_, DI_ / 64, NSEG - 1), 256, 0, stream>>>(pbuf, xcbb, dw, db, Al,
                                                                   hend, send);
    k_scan_full<<<dim3(B_, DI_ / 64, NSEG), 256, 0, stream>>>(pbuf, xcbb, xzb, dw, db, Al,
                                                              D_skip + dp * DI_, hend, send, ybuf);
    k_gemm<64,64,1,0><<<dim3(M_ / 64, 6), 256, 0, stream>>>(ybuf, owt, xbuf, D_, DI_, nullptr, nullptr);
  }

  k_feat_part<<<dim3(B_, 7), 384, 0, stream>>>(xbuf, partial);
  k_head<<<dim3((NC_ + 255) / 256, B_), 256, 0, stream>>>(partial, norm_g, norm_b, head_w, head_b, out);
}

// Round 17
// 1326.863 us; speedup vs baseline: 1.0333x; 1.0035x over previous
//
#include <hip/hip_runtime.h>
#include <math.h>

typedef short bf16x8 __attribute__((ext_vector_type(8)));
typedef float f32x4 __attribute__((ext_vector_type(4)));
typedef float f32x2 __attribute__((ext_vector_type(2)));
typedef unsigned short u16;
typedef unsigned int u32;
typedef unsigned short u16x4 __attribute__((ext_vector_type(4)));

#define B_    32
#define D_    384
#define DEPTH 12
#define NST   16
#define DI_   768
#define R_    24
#define L_    196
#define NC_   1000
#define M_    (B_*L_)   // 6272
#define SEG   28
#define NSEG  7

__device__ __forceinline__ u16 f2bf(float f) {
  union { float f; unsigned u; } v; v.f = f;
  unsigned r = v.u + 0x7fffu + ((v.u >> 16) & 1u);
  return (u16)(r >> 16);
}
__device__ __forceinline__ float bf2f(u16 x) {
  union { unsigned u; float f; } v; v.u = ((unsigned)x) << 16;
  return v.f;
}
__device__ __forceinline__ float quad_sum(float y) {
  y += __int_as_float(__builtin_amdgcn_update_dpp(0, __float_as_int(y), 0xB1, 0xf, 0xf, true));
  y += __int_as_float(__builtin_amdgcn_update_dpp(0, __float_as_int(y), 0x4E, 0xf, 0xf, true));
  return y;
}
__device__ __forceinline__ float exp2fast(float x) {
  return __builtin_amdgcn_exp2f(x);
}

// ---------------- weight prep ----------------
__global__ void k_transpose_bf16(const float* __restrict__ in, u16* __restrict__ out,
                                 int R, int C) {
  __shared__ float tile[32][33];
  const size_t zoff = (size_t)blockIdx.z * R * C;
  in  += zoff; out += zoff;
  int c0 = blockIdx.x * 32, r0 = blockIdx.y * 32;
  int tx = threadIdx.x, ty = threadIdx.y;
  for (int i = ty; i < 32; i += 8) {
    int r = r0 + i, c = c0 + tx;
    tile[i][tx] = (r < R && c < C) ? in[(size_t)r * C + c] : 0.f;
  }
  __syncthreads();
  for (int i = ty; i < 32; i += 8) {
    int c = c0 + i, r = r0 + tx;
    if (c < C && r < R) out[(size_t)c * R + r] = f2bf(tile[tx][i]);
  }
}

// patch_w -> bf16 AND A2 = -exp(A_log)*log2e, one dispatch
__global__ void k_prep_misc(const float* __restrict__ pw, u16* __restrict__ pwb,
                            const float* __restrict__ alog, float* __restrict__ A,
                            int n1, int n2) {
  int i = blockIdx.x * 256 + threadIdx.x;
  if (i < n1) pwb[i] = f2bf(pw[i]);
  else if (i < n1 + n2) {
    int j = i - n1;
    A[j] = -__expf(alog[j]) * 1.44269504088896340736f;
  }
}

// ---------------- im2col ----------------
__global__ void k_im2col(const float* __restrict__ x, u16* __restrict__ xcol) {
  int idx = blockIdx.x * 256 + threadIdx.x;
  if (idx >= M_ * 768) return;
  int k = idx % 768, m = idx / 768;
  int b = m / L_, l = m % L_;
  int li = l / 14, lj = l % 14;
  int c = k / 256, r = k % 256;
  int i = r / 16, j = r % 16;
  int hh = li * 16 + i, ww = lj * 16 + j;
  xcol[idx] = f2bf(x[(((size_t)b * 3 + c) * 224 + hh) * 224 + ww]);
}

// ---------------- GEMM (software-pipelined) ----------------
template<int BM, int BN, int EPI, int OB>
__global__ __launch_bounds__(256)
void k_gemm(const u16* __restrict__ A, const u16* __restrict__ BT,
            float* __restrict__ Cout, int Nn, int Kk,
            const float* __restrict__ bias, const float* __restrict__ pos) {
  const int m0 = blockIdx.x * BM;
  const int n0 = blockIdx.y * BN;
  __shared__ u16 lA[BM * 72];
  __shared__ u16 lB[BN * 72];
  const int tid  = threadIdx.x;
  const int wave = tid >> 6, lane = tid & 63;
  const int wm = (wave >> 1) * (BM / 2), wn = (wave & 1) * (BN / 2);
  constexpr int MI = BM / 32, NJ = BN / 32;
  constexpr int NV = (BM + BN) / 32;
  f32x4 acc[MI][NJ] = {};
  const int fr = lane & 15, kg = (lane >> 4) * 8;

  bf16x8 v[NV];
  auto load = [&](int k0) {
    #pragma unroll
    for (int q = 0; q < NV; ++q) {
      int id = tid + q * 256;
      int row = id >> 3, vv = id & 7;
      bf16x8 t = {};
      if (row < BM) {
        t = *(const bf16x8*)(A + (size_t)(m0 + row) * Kk + k0 + vv * 8);
      } else {
        int br = n0 + row - BM;
        if (br < Nn) t = *(const bf16x8*)(BT + (size_t)br * Kk + k0 + vv * 8);
      }
      v[q] = t;
    }
  };
  load(0);
  for (int k0 = 0; k0 < Kk; k0 += 64) {
    __syncthreads();
    #pragma unroll
    for (int q = 0; q < NV; ++q) {
      int id = tid + q * 256;
      int row = id >> 3, vv = id & 7;
      u16* dst = (row < BM) ? (lA + row * 72 + vv * 8) : (lB + (size_t)(row - BM) * 72 + vv * 8);
      *(bf16x8*)dst = v[q];
    }
    __syncthreads();
    if (k0 + 64 < Kk) load(k0 + 64);
    #pragma unroll
    for (int kk = 0; kk < 64; kk += 32) {
      bf16x8 af[MI], bfr[NJ];
      #pragma unroll
      for (int i = 0; i < MI; ++i)
        af[i] = *(const bf16x8*)(lA + (wm + i * 16 + fr) * 72 + kk + kg);
      #pragma unroll
      for (int j = 0; j < NJ; ++j)
        bfr[j] = *(const bf16x8*)(lB + (wn + j * 16 + fr) * 72 + kk + kg);
      #pragma unroll
      for (int i = 0; i < MI; ++i)
        #pragma unroll
        for (int j = 0; j < NJ; ++j)
          acc[i][j] = __builtin_amdgcn_mfma_f32_16x16x32_bf16(af[i], bfr[j], acc[i][j], 0, 0, 0);
    }
  }

  const int rg = (lane >> 4) * 4;
  #pragma unroll
  for (int i = 0; i < MI; ++i) {
    int row = m0 + wm + i * 16 + rg;
    #pragma unroll
    for (int j = 0; j < NJ; ++j) {
      int col = n0 + wn + j * 16 + fr;
      if (col >= Nn) continue;
      #pragma unroll
      for (int r = 0; r < 4; ++r) {
        float vv = acc[i][j][r];
        size_t idx = (size_t)(row + r) * Nn + col;
        if (EPI == 0) {
          if (OB) ((u16*)Cout)[idx] = f2bf(vv);
          else    Cout[idx] = vv;
        }
        else if (EPI == 1) Cout[idx] += vv;
        else               Cout[idx] = vv + bias[col] + pos[(size_t)((row + r) % L_) * Nn + col];
      }
    }
  }
}

// ---------------- fused conv+SiLU + xp skinny GEMM (K-split x4) ----------------
__global__ __launch_bounds__(256)
void k_xp_conv(const u16* __restrict__ xzb, const float* __restrict__ cw,
               const float* __restrict__ cb, const u16* __restrict__ BT,
               u16* __restrict__ xcb, float* __restrict__ pbuf) {
  const int m0  = blockIdx.x * 32;
  const int ks  = blockIdx.y;
  const int ch0 = ks * 192;
  __shared__ u16 sXZ[35][64];
  __shared__ u16 lA[32 * 72];
  __shared__ u16 lB[64 * 72];
  const int tid  = threadIdx.x;
  const int wave = tid >> 6, lane = tid & 63;
  const int wm = (wave >> 1) * 16, wn = (wave & 1) * 32;
  const int fr = lane & 15, kg = (lane >> 4) * 8;
  f32x4 acc[2] = {};

  for (int kc = 0; kc < 3; ++kc) {
    const int c0 = ch0 + kc * 64;
    __syncthreads();
    #pragma unroll
    for (int j = 0; j < 2; ++j) {
      int u = tid + j * 256;
      if (u < 448) {
        int row = u >> 3, vv = u & 7;
        *(bf16x8*)(lB + row * 72 + vv * 8) =
            *(const bf16x8*)(BT + (size_t)row * DI_ + c0 + vv * 8);
      }
    }
    #pragma unroll
    for (int j = 0; j < 3; ++j) {
      int u = tid + j * 256;
      if (u < 560) {
        int row = u >> 4, c4 = (u & 15) * 4;
        int gm = m0 - 3 + row; if (gm < 0) gm = 0;
        *(u16x4*)&sXZ[row][c4] = *(const u16x4*)(xzb + (size_t)gm * 1536 + c0 + c4);
      }
    }
    __syncthreads();
    #pragma unroll
    for (int j = 0; j < 2; ++j) {
      int g = tid + j * 256;
      int r = g >> 4, c4 = (g & 15) * 4;
      int l = (m0 + r) % L_;
      u16x4 t0 = *(const u16x4*)&sXZ[r + 3][c4];
      u16x4 t1 = (l >= 1) ? *(const u16x4*)&sXZ[r + 2][c4] : u16x4{};
      u16x4 t2 = (l >= 2) ? *(const u16x4*)&sXZ[r + 1][c4] : u16x4{};
      u16x4 t3 = (l >= 3) ? *(const u16x4*)&sXZ[r    ][c4] : u16x4{};
      f32x4 bv = *(const f32x4*)(cb + c0 + c4);
      u16x4 outv;
      #pragma unroll
      for (int c = 0; c < 4; ++c) {
        f32x4 w = *(const f32x4*)(cw + (size_t)(c0 + c4 + c) * 4);
        float a = bv[c] + w[3] * bf2f(t0[c]) + w[2] * bf2f(t1[c])
                        + w[1] * bf2f(t2[c]) + w[0] * bf2f(t3[c]);
        float s = a / (1.f + __expf(-a));
        outv[c] = f2bf(s);
      }
      *(u16x4*)(xcb + (size_t)(m0 + r) * DI_ + c0 + c4) = outv;
      *(u16x4*)(lA + r * 72 + c4) = outv;
    }
    __syncthreads();
    #pragma unroll
    for (int kk = 0; kk < 64; kk += 32) {
      bf16x8 af = *(const bf16x8*)(lA + (wm + fr) * 72 + kk + kg);
      bf16x8 b0 = *(const bf16x8*)(lB + (wn + fr) * 72 + kk + kg);
      bf16x8 b1 = *(const bf16x8*)(lB + (wn + 16 + fr) * 72 + kk + kg);
      acc[0] = __builtin_amdgcn_mfma_f32_16x16x32_bf16(af, b0, acc[0], 0, 0, 0);
      acc[1] = __builtin_amdgcn_mfma_f32_16x16x32_bf16(af, b1, acc[1], 0, 0, 0);
    }
  }
  const int rg = (lane >> 4) * 4;
  #pragma unroll
  for (int j = 0; j < 2; ++j) {
    int col = wn + j * 16 + fr;
    if (col >= 56) continue;
    #pragma unroll
    for (int r = 0; r < 4; ++r) {
      int row = wm + rg + r;
      pbuf[((size_t)ks * M_ + m0 + row) * 56 + col] = acc[j][r];
    }
  }
}

// ---------------- LayerNorm ----------------
__global__ __launch_bounds__(384)
void k_ln(const float* __restrict__ x, const float* __restrict__ g,
          const float* __restrict__ bt, u16* __restrict__ h) {
  const int m = blockIdx.x, d = threadIdx.x;
  __shared__ float red[12];
  float v = x[(size_t)m * D_ + d];
  float s = v, s2 = v * v;
  #pragma unroll
  for (int o = 32; o > 0; o >>= 1) { s += __shfl_xor(s, o); s2 += __shfl_xor(s2, o); }
  int wid = d >> 6;
  if ((d & 63) == 0) { red[wid] = s; red[6 + wid] = s2; }
  __syncthreads();
  float ts = 0.f, ts2 = 0.f;
  #pragma unroll
  for (int w = 0; w < 6; ++w) { ts += red[w]; ts2 += red[6 + w]; }
  float mu = ts / (float)D_;
  float var = ts2 / (float)D_ - mu * mu;
  float rs = rsqrtf(var + 1e-5f);
  h[(size_t)m * D_ + d] = f2bf((v - mu) * rs * g[d] + bt[d]);
}

// ---------------- pass 1: per-segment state only (h_end, scum_end) ----------------
__global__ __launch_bounds__(256)
void k_scan_state(const float* __restrict__ pbuf, const u16* __restrict__ xcb,
                  const float* __restrict__ dtw, const float* __restrict__ dtb,
                  const float* __restrict__ Abuf, float* __restrict__ hend,
                  float* __restrict__ send) {
  const int b   = blockIdx.x;
  const int di0 = blockIdx.y * 64;
  const int s   = blockIdx.z;
  const int tid = threadIdx.x;
  const int dil = tid >> 2, nq = tid & 3;
  const int di  = di0 + dil;
  __shared__ float sDT[SEG][64];
  __shared__ u16   sXC[SEG][64];
  __shared__ float sB [SEG][16];
  __shared__ float sdb[SEG][28];

  const f32x4 Arow = *(const f32x4*)(Abuf + (size_t)di * NST + nq * 4);
  const size_t mb = (size_t)b * L_ + (size_t)s * SEG;
  const int chd = tid & 63;

  {
    int r = tid >> 4, cc = (tid & 15) * 4;
    #pragma unroll
    for (int j = 0; j < 2; ++j) {
      int row = r + j * 16;
      if (row < SEG)
        *(u16x4*)&sXC[row][cc] = *(const u16x4*)(xcb + (mb + row) * DI_ + di0 + cc);
    }
    if (tid < SEG * 6) {
      int row = tid / 6, c4 = (tid % 6) * 4;
      f32x4 ssum = {};
      #pragma unroll
      for (int ks = 0; ks < 4; ++ks)
        ssum += *(const f32x4*)(pbuf + ((size_t)ks * M_ + mb + row) * 56 + c4);
      *(f32x4*)&sdb[row][c4] = ssum;
    }
    if (tid < SEG * 4) {
      int row = tid >> 2, c4 = (tid & 3) * 4;
      f32x4 ssum = {};
      #pragma unroll
      for (int ks = 0; ks < 4; ++ks)
        ssum += *(const f32x4*)(pbuf + ((size_t)ks * M_ + mb + row) * 56 + 24 + c4);
      *(f32x4*)&sB[row][c4] = ssum;
    }
  }
  float w[24];
  #pragma unroll
  for (int r = 0; r < 24; ++r) w[r] = dtw[r * DI_ + di0 + chd];
  const float bvd = dtb[di0 + chd];
  __syncthreads();

  {
    const int rg = tid >> 6;
    #pragma unroll
    for (int rr = 0; rr < 7; ++rr) {
      int row = rg * 7 + rr;
      float acc = bvd;
      #pragma unroll
      for (int r4 = 0; r4 < 6; ++r4) {
        f32x4 sv = *(const f32x4*)&sdb[row][r4 * 4];
        acc += sv[0] * w[r4 * 4] + sv[1] * w[r4 * 4 + 1]
             + sv[2] * w[r4 * 4 + 2] + sv[3] * w[r4 * 4 + 3];
      }
      float e  = __expf(-fabsf(acc));
      sDT[row][chd] = fmaxf(acc, 0.f) + __logf(1.f + e);
    }
  }
  __syncthreads();

  __builtin_amdgcn_s_setprio(1);     // favor serial recurrence waves
  float h[4] = {0.f, 0.f, 0.f, 0.f};
  float scum = 0.f;
  float dtc = sDT[0][dil], xcc = bf2f(sXC[0][dil]);
  f32x4 Bv = *(const f32x4*)&sB[0][nq * 4];
  #pragma unroll 4
  for (int t = 0; t < SEG; ++t) {
    float dtn = 0.f, xcn = 0.f; f32x4 Bn = {};
    if (t + 1 < SEG) {
      dtn = sDT[t + 1][dil]; xcn = bf2f(sXC[t + 1][dil]);
      Bn = *(const f32x4*)&sB[t + 1][nq * 4];
    }
    scum += dtc;
    float dxv = dtc * xcc;
    #pragma unroll
    for (int n = 0; n < 4; ++n) {
      float e = exp2fast(dtc * Arow[n]);
      h[n] = e * h[n] + dxv * Bv[n];
    }
    dtc = dtn; xcc = xcn; Bv = Bn;
  }
  __builtin_amdgcn_s_setprio(0);

  size_t sb = ((size_t)s * B_ + b) * DI_ + di;
  *(f32x4*)(hend + sb * 16 + nq * 4) = f32x4{h[0], h[1], h[2], h[3]};
  if (nq == 0) send[sb] = scum;
}

// ---------------- pass 2: full scan with carry-in + gate -> ybuf ----------------
__global__ __launch_bounds__(256)
void k_scan_full(const float* __restrict__ pbuf, const u16* __restrict__ xcb,
                 const u16* __restrict__ xzb, const float* __restrict__ dtw,
                 const float* __restrict__ dtb, const float* __restrict__ Abuf,
                 const float* __restrict__ Dsk, const float* __restrict__ hend,
                 const float* __restrict__ send, u16* __restrict__ yb) {
  const int b   = blockIdx.x;
  const int di0 = blockIdx.y * 64;
  const int s   = blockIdx.z;
  const int tid = threadIdx.x;
  const int dil = tid >> 2, nq = tid & 3;
  const int di  = di0 + dil;
  __shared__ float sDT[SEG][64];
  __shared__ u16   sXC[SEG][64];
  __shared__ float sBC[SEG][32];
  __shared__ __align__(16) u16 sYO[SEG][64];
  float (*sdb)[28] = (float(*)[28])&sYO[0][0];

  const f32x4 Arow = *(const f32x4*)(Abuf + (size_t)di * NST + nq * 4);
  const float Dv = Dsk[di];
  const size_t mb = (size_t)b * L_ + (size_t)s * SEG;
  const int chd = tid & 63;

  {
    int r = tid >> 4, cc = (tid & 15) * 4;
    #pragma unroll
    for (int j = 0; j < 2; ++j) {
      int row = r + j * 16;
      if (row < SEG)
        *(u16x4*)&sXC[row][cc] = *(const u16x4*)(xcb + (mb + row) * DI_ + di0 + cc);
    }
    if (tid < SEG * 6) {
      int row = tid / 6, c4 = (tid % 6) * 4;
      f32x4 ssum = {};
      #pragma unroll
      for (int ks = 0; ks < 4; ++ks)
        ssum += *(const f32x4*)(pbuf + ((size_t)ks * M_ + mb + row) * 56 + c4);
      *(f32x4*)&sdb[row][c4] = ssum;
    }
    if (tid < SEG * 8) {
      int row = tid >> 3, c4 = (tid & 7) * 4;
      f32x4 ssum = {};
      #pragma unroll
      for (int ks = 0; ks < 4; ++ks)
        ssum += *(const f32x4*)(pbuf + ((size_t)ks * M_ + mb + row) * 56 + 24 + c4);
      *(f32x4*)&sBC[row][c4] = ssum;
    }
  }

  float h[4] = {0.f, 0.f, 0.f, 0.f};
  for (int r = 0; r < s; ++r) {
    size_t sb = ((size_t)r * B_ + b) * DI_ + di;
    f32x4 he = *(const f32x4*)(hend + sb * 16 + nq * 4);
    float se = send[sb];
    #pragma unroll
    for (int q = 0; q < 4; ++q) h[q] = exp2fast(Arow[q] * se) * h[q] + he[q];
  }

  float w[24];
  #pragma unroll
  for (int r = 0; r < 24; ++r) w[r] = dtw[r * DI_ + di0 + chd];
  const float bvd = dtb[di0 + chd];
  __syncthreads();

  {
    const int rg = tid >> 6;
    #pragma unroll
    for (int rr = 0; rr < 7; ++rr) {
      int row = rg * 7 + rr;
      float acc = bvd;
      #pragma unroll
      for (int r4 = 0; r4 < 6; ++r4) {
        f32x4 sv = *(const f32x4*)&sdb[row][r4 * 4];
        acc += sv[0] * w[r4 * 4] + sv[1] * w[r4 * 4 + 1]
             + sv[2] * w[r4 * 4 + 2] + sv[3] * w[r4 * 4 + 3];
      }
      float e  = __expf(-fabsf(acc));
      sDT[row][chd] = fmaxf(acc, 0.f) + __logf(1.f + e);
    }
  }
  __syncthreads();   // sdb dead; sYO writes may begin

  __builtin_amdgcn_s_setprio(1);     // favor serial recurrence waves
  float dtc = sDT[0][dil], xcc = bf2f(sXC[0][dil]);
  f32x4 Bv = *(const f32x4*)&sBC[0][nq * 4];
  f32x4 Cv = *(const f32x4*)&sBC[0][16 + nq * 4];
  #pragma unroll 4
  for (int t = 0; t < SEG; ++t) {
    float dtn = 0.f, xcn = 0.f; f32x4 Bn = {}, Cn = {};
    if (t + 1 < SEG) {
      dtn = sDT[t + 1][dil]; xcn = bf2f(sXC[t + 1][dil]);
      Bn = *(const f32x4*)&sBC[t + 1][nq * 4];
      Cn = *(const f32x4*)&sBC[t + 1][16 + nq * 4];
    }
    float dxv = dtc * xcc;
    float y = 0.f;
    #pragma unroll
    for (int n = 0; n < 4; ++n) {
      float e = exp2fast(dtc * Arow[n]);
      h[n] = e * h[n] + dxv * Bv[n];
      y += h[n] * Cv[n];
    }
    y = quad_sum(y);
    if (nq == 0) sYO[t][dil] = f2bf(y + Dv * xcc);
    dtc = dtn; xcc = xcn; Bv = Bn; Cv = Cn;
  }
  __builtin_amdgcn_s_setprio(0);
  __syncthreads();

  #pragma unroll
  for (int j = 0; j < 4; ++j) {
    int id = tid + j * 256;
    if (id < SEG * 32) {
      int row = id >> 5, c2 = id & 31;
      int ch0 = c2 * 2;
      float y0 = bf2f(sYO[row][ch0]), y1 = bf2f(sYO[row][ch0 + 1]);
      u32 zz = *(const u32*)(xzb + (mb + row) * 1536 + DI_ + di0 + ch0);
      float z0 = bf2f((u16)(zz & 0xffff)), z1 = bf2f((u16)(zz >> 16));
      u32 o = (u32)f2bf(y0 * z0 / (1.f + __expf(-z0)))
            | ((u32)f2bf(y1 * z1 / (1.f + __expf(-z1))) << 16);
      *((u32*)yb + ((mb + row) * DI_ + di0) / 2 + c2) = o;
    }
  }
}

// ---------------- final LN partial sums ----------------
__global__ __launch_bounds__(384)
void k_feat_part(const float* __restrict__ x, float* __restrict__ partial) {
  const int b = blockIdx.x, j = blockIdx.y, d = threadIdx.x;
  __shared__ float red[12];
  const int l0 = j * 28;
  float acc = 0.f;
  float v = x[((size_t)b * L_ + l0) * D_ + d];
  for (int l = l0; l < l0 + 28; ++l) {
    float vn = (l + 1 < l0 + 28) ? x[((size_t)b * L_ + l + 1) * D_ + d] : 0.f;
    float s = v, s2 = v * v;
    #pragma unroll
    for (int o = 32; o > 0; o >>= 1) { s += __shfl_xor(s, o); s2 += __shfl_xor(s2, o); }
    int wid = d >> 6;
    if ((d & 63) == 0) { red[wid] = s; red[6 + wid] = s2; }
    __syncthreads();
    float ts = 0.f, ts2 = 0.f;
    #pragma unroll
    for (int w = 0; w < 6; ++w) { ts += red[w]; ts2 += red[6 + w]; }
    float mu = ts * (1.f / (float)D_);
    float var = ts2 * (1.f / (float)D_) - mu * mu;
    acc += (v - mu) * rsqrtf(var + 1e-5f);
    __syncthreads();
    v = vn;
  }
  partial[((size_t)(b * 7 + j)) * D_ + d] = acc;
}

// ---------------- head ----------------
__global__ __launch_bounds__(256)
void k_head(const float* __restrict__ partial, const float* __restrict__ g,
            const float* __restrict__ bt, const float* __restrict__ hw,
            const float* __restrict__ hb, float* __restrict__ out) {
  const int b = blockIdx.y;
  const int c = blockIdx.x * 256 + threadIdx.x;
  __shared__ float sf[D_];
  for (int i = threadIdx.x; i < D_; i += 256) {
    float s = 0.f;
    #pragma unroll
    for (int j = 0; j < 7; ++j) s += partial[((size_t)(b * 7 + j)) * D_ + i];
    sf[i] = g[i] * (s * (1.f / (float)L_)) + bt[i];
  }
  __syncthreads();
  if (c >= NC_) return;
  float acc = hb[c];
  for (int d = 0; d < D_; ++d) acc += sf[d] * hw[(size_t)d * NC_ + c];
  out[(size_t)b * NC_ + c] = acc;
}

// =====================================================================
extern "C" void kernel_launch(void* const* d_in, const int* in_sizes, int n_in,
                              void* d_out, int out_size, void* d_ws, size_t ws_size,
                              hipStream_t stream) {
  const float* x_in    = (const float*)d_in[0];
  const float* patch_w = (const float*)d_in[1];
  const float* patch_b = (const float*)d_in[2];
  const float* pos     = (const float*)d_in[3];
  const float* bn_g    = (const float*)d_in[4];
  const float* bn_b    = (const float*)d_in[5];
  const float* in_w    = (const float*)d_in[6];
  const float* conv_w  = (const float*)d_in[7];
  const float* conv_b  = (const float*)d_in[8];
  const float* xp_w    = (const float*)d_in[9];
  const float* dtp_w   = (const float*)d_in[10];
  const float* dtp_b   = (const float*)d_in[11];
  const float* A_log   = (const float*)d_in[12];
  const float* D_skip  = (const float*)d_in[13];
  const float* out_w   = (const float*)d_in[14];
  const float* norm_g  = (const float*)d_in[15];
  const float* norm_b  = (const float*)d_in[16];
  const float* head_w  = (const float*)d_in[17];
  const float* head_b  = (const float*)d_in[18];
  float* out = (float*)d_out;

  char* ws = (char*)d_ws;
  size_t off = 0;
  auto alloc = [&](size_t bytes) { size_t o = off; off += (bytes + 255) & ~(size_t)255; return o; };

  float* xbuf   = (float*)(ws + alloc((size_t)M_ * D_ * 4));
  u16*   hbuf   = (u16*)  (ws + alloc((size_t)M_ * D_ * 2));
  u16*   xzb    = (u16*)  (ws + alloc((size_t)M_ * 1536 * 2));
  u16*   xcbb   = (u16*)  (ws + alloc((size_t)M_ * DI_ * 2));
  float* pbuf   = (float*)(ws + alloc((size_t)4 * M_ * 56 * 4));
  u16*   im2col = (u16*)  (ws + alloc((size_t)M_ * 768 * 2));
  u16*   ybuf   = (u16*)  (ws + alloc((size_t)M_ * DI_ * 2));
  float* hend   = (float*)(ws + alloc((size_t)NSEG * B_ * DI_ * NST * 4));
  float* send   = (float*)(ws + alloc((size_t)NSEG * B_ * DI_ * 4));
  float* Abuf   = (float*)(ws + alloc((size_t)DEPTH * DI_ * NST * 4));
  float* partial= (float*)(ws + alloc((size_t)B_ * 7 * D_ * 4));
  u16*   in_wT  = (u16*)  (ws + alloc((size_t)DEPTH * 1536 * D_ * 2));
  u16*   xp_wT  = (u16*)  (ws + alloc((size_t)DEPTH * 56 * DI_ * 2));
  u16*   out_wT = (u16*)  (ws + alloc((size_t)DEPTH * D_ * DI_ * 2));
  u16*   pw_b   = (u16*)  (ws + alloc((size_t)D_ * 768 * 2));

  dim3 tb(32, 8);
  k_transpose_bf16<<<dim3(48, 12, DEPTH), tb, 0, stream>>>(in_w,  in_wT,  D_, 1536);
  k_transpose_bf16<<<dim3(2, 24, DEPTH),  tb, 0, stream>>>(xp_w,  xp_wT,  DI_, 56);
  k_transpose_bf16<<<dim3(12, 24, DEPTH), tb, 0, stream>>>(out_w, out_wT, DI_, D_);
  {
    int n1 = D_ * 768, n2 = DEPTH * DI_ * NST;
    k_prep_misc<<<(n1 + n2 + 255) / 256, 256, 0, stream>>>(patch_w, pw_b, A_log, Abuf, n1, n2);
  }

  k_im2col<<<(M_ * 768 + 255) / 256, 256, 0, stream>>>(x_in, im2col);
  k_gemm<64,64,2,0><<<dim3(M_ / 64, 6), 256, 0, stream>>>(im2col, pw_b, xbuf, D_, 768, patch_b, pos);

  for (int dp = 0; dp < DEPTH; ++dp) {
    const u16* iwt = in_wT  + (size_t)dp * 1536 * D_;
    const u16* xwt = xp_wT  + (size_t)dp * 56 * DI_;
    const u16* owt = out_wT + (size_t)dp * D_ * DI_;
    const float* Al = Abuf + (size_t)dp * DI_ * NST;
    const float* dw = dtp_w + (size_t)dp * R_ * DI_;
    const float* db = dtp_b + dp * DI_;
    k_ln<<<M_, 384, 0, stream>>>(xbuf, bn_g + dp * D_, bn_b + dp * D_, hbuf);
    k_gemm<64,128,0,1><<<dim3(M_ / 64, 12), 256, 0, stream>>>(hbuf, iwt, (float*)xzb, 1536, D_, nullptr, nullptr);
    k_xp_conv<<<dim3(M_ / 32, 4), 256, 0, stream>>>(xzb, conv_w + (size_t)dp * DI_ * 4,
                                                    conv_b + dp * DI_, xwt, xcbb, pbuf);
    k_scan_state<<<dim3(B_, DI_ / 64, NSEG - 1), 256, 0, stream>>>(pbuf, xcbb, dw, db, Al,
                                                                   hend, send);
    k_scan_full<<<dim3(B_, DI_ / 64, NSEG), 256, 0, stream>>>(pbuf, xcbb, xzb, dw, db, Al,
                                                              D_skip + dp * DI_, hend, send, ybuf);
    k_gemm<64,64,1,0><<<dim3(M_ / 64, 6), 256, 0, stream>>>(ybuf, owt, xbuf, D_, DI_, nullptr, nullptr);
  }

  k_feat_part<<<dim3(B_, 7), 384, 0, stream>>>(xbuf, partial);
  k_head<<<dim3((NC_ + 255) / 256, B_), 256, 0, stream>>>(partial, norm_g, norm_b, head_w, head_b, out);
}